// Round 2
// baseline (1418.443 us; speedup 1.0000x reference)
//
#include <hip/hip_runtime.h>
#include <hip/hip_fp16.h>

// PerformerAttention fused pipeline, MI355X (gfx950).
// B=8 N=4096 C=768 H=12 DH=64 M=256, fp32 in/out, fp16 MFMA for GEMMs.
// Round 1 fix: workspace 569MB -> ~216MB (round 0 crash = suspected d_ws
// overflow). qkv stored fp16 head-major; one 50MB region time-shared by
// x_h -> kvpart -> attn; LayerNorm in-place on d_out.

#define LOG2E 1.44269504088896340736f

typedef _Float16 half8 __attribute__((ext_vector_type(8)));
typedef _Float16 half4_t __attribute__((ext_vector_type(4)));
typedef _Float16 half2_t __attribute__((ext_vector_type(2)));
typedef float f32x4 __attribute__((ext_vector_type(4)));

#if __has_builtin(__builtin_amdgcn_fdot2)
#define FDOT2(a, b, c) __builtin_amdgcn_fdot2((a), (b), (c), false)
#else
#define FDOT2(a, b, c) \
  ((float)(a)[0] * (float)(b)[0] + ((float)(a)[1] * (float)(b)[1] + (c)))
#endif

// ---------------- casts ----------------

__global__ __launch_bounds__(256) void cast_f32_f16(const float* __restrict__ in,
                                                    _Float16* __restrict__ out, long n) {
  long i = ((long)blockIdx.x * 256 + threadIdx.x) * 4;
  if (i + 3 < n) {
    float4 v = *(const float4*)(in + i);
    half4_t h;
    h[0] = (_Float16)v.x; h[1] = (_Float16)v.y; h[2] = (_Float16)v.z; h[3] = (_Float16)v.w;
    *(half4_t*)(out + i) = h;
  } else {
    for (long j = i; j < n && j < i + 4; ++j) out[j] = (_Float16)in[j];
  }
}

// in [K, Nt] fp32 -> out [Nt, K] fp16
__global__ __launch_bounds__(256) void cast_transpose(const float* __restrict__ in,
                                                      _Float16* __restrict__ out,
                                                      int K, int Nt) {
  long i = (long)blockIdx.x * 256 + threadIdx.x;
  if (i >= (long)K * Nt) return;
  int n = (int)(i % Nt);
  int k = (int)(i / Nt);
  out[(long)n * K + k] = (_Float16)in[i];
}

// ---------------- MFMA GEMM (m97-style, 128x128x32, fp16 in) ----------------
// A [Mr,K] row-major fp16, BT [Ntot,K] row-major fp16. K % 32 == 0.
// EPI==1: Co = A@B + bias[col] + resid[row,col]  (fp32, proj+residual)
// EPI==2: scatter fp16 into qh/kh/vh head-major [bh][n][64]  (qkv GEMM)

__device__ __forceinline__ void glds16(const _Float16* g, _Float16* s) {
  __builtin_amdgcn_global_load_lds(
      (const __attribute__((address_space(1))) void*)g,
      (__attribute__((address_space(3))) unsigned int*)s,
      16, 0, 0);
}

template <int EPI>
__global__ __launch_bounds__(256)
void gemm_f16(const _Float16* __restrict__ A, const _Float16* __restrict__ BT,
              float* __restrict__ Co, int Mr, int Ntot, int K,
              const float* __restrict__ bias, const float* __restrict__ resid,
              _Float16* __restrict__ qh, _Float16* __restrict__ kh,
              _Float16* __restrict__ vh) {
  __shared__ __align__(16) _Float16 As[128 * 32];
  __shared__ __align__(16) _Float16 Bs[128 * 32];
  const int tid = threadIdx.x;
  const int w = tid >> 6;       // wave 0..3
  const int l = tid & 63;
  const int lr = l & 15;
  const int kg = l >> 4;        // 0..3
  const int m0 = blockIdx.y * 128;
  const int n0 = blockIdx.x * 128;
  const int wm = (w >> 1) * 64; // wave's 64x64 sub-tile
  const int wn = (w & 1) * 64;

  // staging: wave w covers 32 rows/tile; lane i -> row base+i/4, col (i%4)*8
  // (glds16 dest = wave-uniform base + lane*16B, matching this layout)
  const _Float16* gA = A + (long)(m0 + w * 32 + (l >> 2)) * K + (l & 3) * 8;
  const _Float16* gB = BT + (long)(n0 + w * 32 + (l >> 2)) * K + (l & 3) * 8;
  _Float16* sA = As + (w * 32) * 32;
  _Float16* sB = Bs + (w * 32) * 32;

  f32x4 acc[4][4];
#pragma unroll
  for (int t = 0; t < 4; ++t)
#pragma unroll
    for (int u = 0; u < 4; ++u) acc[t][u] = (f32x4){0.f, 0.f, 0.f, 0.f};

  const int nK = K >> 5;
  for (int kc = 0; kc < nK; ++kc) {
    __syncthreads();
    glds16(gA, sA);
    glds16(gA + 16 * K, sA + 16 * 32);
    glds16(gB, sB);
    glds16(gB + 16 * K, sB + 16 * 32);
    gA += 32; gB += 32;
    __syncthreads();  // compiler drains vmcnt(0) before barrier

    half8 af[4], bf[4];
#pragma unroll
    for (int t = 0; t < 4; ++t)
      af[t] = *(const half8*)(As + (wm + t * 16 + lr) * 32 + kg * 8);
#pragma unroll
    for (int u = 0; u < 4; ++u)
      bf[u] = *(const half8*)(Bs + (wn + u * 16 + lr) * 32 + kg * 8);
#pragma unroll
    for (int t = 0; t < 4; ++t)
#pragma unroll
      for (int u = 0; u < 4; ++u)
        acc[t][u] = __builtin_amdgcn_mfma_f32_16x16x32_f16(af[t], bf[u], acc[t][u], 0, 0, 0);
  }

  // C/D layout: col = lane&15, row = (lane>>4)*4 + reg  [m89-verified]
#pragma unroll
  for (int t = 0; t < 4; ++t)
#pragma unroll
    for (int u = 0; u < 4; ++u) {
      const int row = m0 + wm + t * 16 + kg * 4;
      const int col = n0 + wn + u * 16 + lr;
#pragma unroll
      for (int r = 0; r < 4; ++r) {
        float v = acc[t][u][r];
        if (EPI == 1) {
          long idx = (long)(row + r) * Ntot + col;
          Co[idx] = v + bias[col] + resid[idx];
        } else {
          // which buffer / head / dim from col in [0,2304)
          const int which = (col >= 1536) ? 2 : ((col >= 768) ? 1 : 0);
          const int c2 = col - which * 768;
          const int h = c2 >> 6, d = c2 & 63;
          _Float16* dst = (which == 0) ? qh : ((which == 1) ? kh : vh);
          const int rr = row + r;
          const long o = (((long)((rr >> 12) * 12 + h)) * 4096 + (rr & 4095)) * 64 + d;
          dst[o] = (_Float16)v;
        }
      }
    }
}

// ---------------- norm_sq: 0.5*||q||^2, 0.5*||k||^2 per (bh,n) ----------------

__global__ __launch_bounds__(256)
void nsq_kernel(const _Float16* __restrict__ qh, const _Float16* __restrict__ kh,
                float* __restrict__ nsq_q, float* __restrict__ nsq_k) {
  long idx = (long)blockIdx.x * 256 + threadIdx.x;  // 96*4096
  const long base = idx * 64;
  float sq = 0.f, sk = 0.f;
#pragma unroll
  for (int d = 0; d < 64; d += 8) {
    half8 a = *(const half8*)(qh + base + d);
    half8 c = *(const half8*)(kh + base + d);
#pragma unroll
    for (int j = 0; j < 8; ++j) {
      float fa = (float)a[j], fc = (float)c[j];
      sq += fa * fa;
      sk += fc * fc;
    }
  }
  nsq_q[idx] = 0.5f * sq;
  nsq_k[idx] = 0.5f * sk;
}

// ---------------- stage 2: kv[m,d], k_sum[m] partials (thread <-> m) ----------------

__global__ __launch_bounds__(256)
void kv_partial(const _Float16* __restrict__ kh, const _Float16* __restrict__ vh,
                const _Float16* __restrict__ rfh, const float* __restrict__ nsqk,
                float* __restrict__ kvpart, float* __restrict__ kspart) {
  const int chunk = blockIdx.x;  // 0..7, 512 tokens each
  const int bh = blockIdx.y;     // 0..95
  const int m = threadIdx.x;

  half2_t rf2[32];
#pragma unroll
  for (int d = 0; d < 8; ++d) {
    half8 t8 = *(const half8*)(rfh + m * 64 + d * 8);
    const half2_t* p2 = (const half2_t*)&t8;
    rf2[d * 4] = p2[0]; rf2[d * 4 + 1] = p2[1];
    rf2[d * 4 + 2] = p2[2]; rf2[d * 4 + 3] = p2[3];
  }
  float kvacc[64];
#pragma unroll
  for (int d = 0; d < 64; ++d) kvacc[d] = 0.f;
  float ks = 0.f;

  const int n0 = chunk * 512;
  const float* nsp = nsqk + (long)bh * 4096 + n0;
  const _Float16* kb = kh + ((long)bh * 4096 + n0) * 64;
  const _Float16* vb = vh + ((long)bh * 4096 + n0) * 64;

  for (int nn = 0; nn < 512; ++nn) {
    const half2_t* kr = (const half2_t*)(kb + (long)nn * 64);
    float p = 0.f;
#pragma unroll
    for (int j = 0; j < 32; ++j) p = FDOT2(kr[j], rf2[j], p);
    const float ph = exp2f((p - nsp[nn]) * LOG2E) * 0.0625f;
    const _Float16* vr = vb + (long)nn * 64;
#pragma unroll
    for (int d = 0; d < 64; d += 8) {
      half8 vv = *(const half8*)(vr + d);
#pragma unroll
      for (int j = 0; j < 8; ++j) kvacc[d + j] += ph * (float)vv[j];
    }
    ks += ph;
  }
  float* op = kvpart + ((long)(bh * 8 + chunk) * 256 + m) * 64;
#pragma unroll
  for (int d = 0; d < 64; d += 4)
    *(float4*)(op + d) = make_float4(kvacc[d], kvacc[d + 1], kvacc[d + 2], kvacc[d + 3]);
  kspart[(bh * 8 + chunk) * 256 + m] = ks;
}

__global__ __launch_bounds__(256)
void reduce_kv(const float* __restrict__ part, float* __restrict__ kvf) {
  long i = (long)blockIdx.x * 256 + threadIdx.x;  // exactly 96*16384
  const int bh = (int)(i >> 14);
  const int md = (int)(i & 16383);
  float s = 0.f;
#pragma unroll
  for (int c = 0; c < 8; ++c) s += part[(((long)bh * 8 + c) << 14) + md];
  kvf[i] = s;
}

__global__ __launch_bounds__(256)
void reduce_ks(const float* __restrict__ part, float* __restrict__ ksf) {
  int i = blockIdx.x * 256 + threadIdx.x;  // exactly 96*256
  int bh = i >> 8, m = i & 255;
  float s = 0.f;
#pragma unroll
  for (int c = 0; c < 8; ++c) s += part[((bh * 8 + c) << 8) + m];
  ksf[i] = s;
}

// ---------------- stage 3: out = phi_q @ kv / (phi_q . k_sum + 1e-6) ----------------
// thread <-> token; writes attention output fp16 [32768,768] for proj GEMM.

__global__ __launch_bounds__(256)
void attn_out(const _Float16* __restrict__ qh, const _Float16* __restrict__ rfh,
              const float* __restrict__ nsqq, const float* __restrict__ kvf,
              const float* __restrict__ ksf, _Float16* __restrict__ attn) {
  const int chunk = blockIdx.x;  // 0..15, 256 tokens each
  const int bh = blockIdx.y;
  const int b = bh / 12, h = bh % 12;
  const int n = chunk * 256 + threadIdx.x;
  const long tok = (long)bh * 4096 + n;

  half2_t q2[32];
#pragma unroll
  for (int d = 0; d < 8; ++d) {
    half8 t8 = *(const half8*)(qh + tok * 64 + d * 8);
    const half2_t* p2 = (const half2_t*)&t8;
    q2[d * 4] = p2[0]; q2[d * 4 + 1] = p2[1];
    q2[d * 4 + 2] = p2[2]; q2[d * 4 + 3] = p2[3];
  }
  float o[64];
#pragma unroll
  for (int d = 0; d < 64; ++d) o[d] = 0.f;
  float norm = 0.f;
  const float nsq = nsqq[tok];
  const float* kvb = kvf + (long)bh * 16384;
  const float* ksb = ksf + bh * 256;

  for (int m = 0; m < 256; ++m) {
    const half2_t* rp = (const half2_t*)(rfh + m * 64);
    float p = 0.f;
#pragma unroll
    for (int j = 0; j < 32; ++j) p = FDOT2(q2[j], rp[j], p);
    const float ph = exp2f((p - nsq) * LOG2E) * 0.0625f;
    const float* kp = kvb + m * 64;
#pragma unroll
    for (int d = 0; d < 64; d += 4) {
      float4 kk = *(const float4*)(kp + d);
      o[d] += ph * kk.x; o[d + 1] += ph * kk.y;
      o[d + 2] += ph * kk.z; o[d + 3] += ph * kk.w;
    }
    norm += ph * ksb[m];
  }
  const float inv = 1.f / (norm + 1e-6f);
  _Float16* op = attn + ((long)b * 4096 + n) * 768 + h * 64;
#pragma unroll
  for (int d = 0; d < 64; d += 8) {
    half8 hv;
#pragma unroll
    for (int j = 0; j < 8; ++j) hv[j] = (_Float16)(o[d + j] * inv);
    *(half8*)(op + d) = hv;
  }
}

// ---------------- LayerNorm: one wave per row of 768 (in-place safe) ----------------

__global__ __launch_bounds__(256)
void ln_kernel(const float* __restrict__ y, const float* __restrict__ gamma,
               const float* __restrict__ beta, float* __restrict__ outp) {
  const int wv = threadIdx.x >> 6, l = threadIdx.x & 63;
  const long row = (long)blockIdx.x * 4 + wv;
  const float* yr = y + row * 768;
  float v[12];
  float s = 0.f;
#pragma unroll
  for (int j = 0; j < 12; ++j) { v[j] = yr[l + j * 64]; s += v[j]; }
#pragma unroll
  for (int off = 32; off; off >>= 1) s += __shfl_xor(s, off);
  const float mu = s * (1.f / 768.f);
  float vs = 0.f;
#pragma unroll
  for (int j = 0; j < 12; ++j) { float d = v[j] - mu; vs += d * d; }
#pragma unroll
  for (int off = 32; off; off >>= 1) vs += __shfl_xor(vs, off);
  const float rstd = rsqrtf(vs * (1.f / 768.f) + 1e-5f);
  float* orp = outp + row * 768;
#pragma unroll
  for (int j = 0; j < 12; ++j)
    orp[l + j * 64] = (v[j] - mu) * rstd * gamma[l + j * 64] + beta[l + j * 64];
}

// ---------------- launch ----------------

extern "C" void kernel_launch(void* const* d_in, const int* in_sizes, int n_in,
                              void* d_out, int out_size, void* d_ws, size_t ws_size,
                              hipStream_t stream) {
  const float* x = (const float*)d_in[0];
  const float* Wqkv = (const float*)d_in[1];
  const float* Wproj = (const float*)d_in[2];
  const float* bproj = (const float*)d_in[3];
  const float* gamma = (const float*)d_in[4];
  const float* beta = (const float*)d_in[5];
  const float* rfm = (const float*)d_in[6];

  char* ws = (char*)d_ws;
  size_t off = 0;
  auto alloc = [&](size_t bytes) -> void* {
    void* p = ws + off;
    off += (bytes + 255) & ~(size_t)255;
    return p;
  };
  // region0: time-shared by x_h (stages 1-4) -> kvpart (6-7) -> attn (9-10)
  char* region0 = (char*)alloc(50331648ULL);
  _Float16* x_h = (_Float16*)region0;
  float* kvpart = (float*)region0;     // 96*8*256*64*4 = 50331648
  _Float16* attn = (_Float16*)region0; // 32768*768*2  = 50331648

  _Float16* wqkvT = (_Float16*)alloc(1769472ULL * 2);   // [2304,768] fp16
  _Float16* wprojT = (_Float16*)alloc(589824ULL * 2);   // [768,768] fp16
  _Float16* rfh = (_Float16*)alloc(16384ULL * 2);       // [256,64] fp16
  _Float16* qh = (_Float16*)alloc(25165824ULL * 2);     // [96][4096][64]
  _Float16* kh = (_Float16*)alloc(25165824ULL * 2);
  _Float16* vh = (_Float16*)alloc(25165824ULL * 2);
  float* nsq_q = (float*)alloc(393216ULL * 4);
  float* nsq_k = (float*)alloc(393216ULL * 4);
  float* kspart = (float*)alloc(96ULL * 8 * 256 * 4);
  float* kvf = (float*)alloc(96ULL * 256 * 64 * 4);
  float* ksf = (float*)alloc(96ULL * 256 * 4);
  // total ~216.4 MB (round 0's 569 MB suspected to exceed ws_size)

  float* y = (float*)d_out;  // proj+residual writes y; LN normalizes in place

  cast_f32_f16<<<24576, 256, 0, stream>>>(x, x_h, 25165824L);
  cast_transpose<<<6912, 256, 0, stream>>>(Wqkv, wqkvT, 768, 2304);
  cast_transpose<<<2304, 256, 0, stream>>>(Wproj, wprojT, 768, 768);
  cast_f32_f16<<<16, 256, 0, stream>>>(rfm, rfh, 16384L);
  gemm_f16<2><<<dim3(18, 256), 256, 0, stream>>>(x_h, wqkvT, nullptr, 32768, 2304, 768,
                                                 nullptr, nullptr, qh, kh, vh);
  nsq_kernel<<<1536, 256, 0, stream>>>(qh, kh, nsq_q, nsq_k);
  kv_partial<<<dim3(8, 96), 256, 0, stream>>>(kh, vh, rfh, nsq_k, kvpart, kspart);
  reduce_kv<<<6144, 256, 0, stream>>>(kvpart, kvf);
  reduce_ks<<<96, 256, 0, stream>>>(kspart, ksf);
  attn_out<<<dim3(16, 96), 256, 0, stream>>>(qh, rfh, nsq_q, kvf, ksf, attn);
  gemm_f16<1><<<dim3(6, 256), 256, 0, stream>>>(attn, wprojT, y, 32768, 768, 768,
                                                bproj, x, nullptr, nullptr, nullptr);
  ln_kernel<<<8192, 256, 0, stream>>>(y, gamma, beta, y);
}

// Round 4
// 659.546 us; speedup vs baseline: 2.1506x; 2.1506x over previous
//
#include <hip/hip_runtime.h>
#include <hip/hip_fp16.h>

// PerformerAttention fused pipeline, MI355X (gfx950).
// B=8 N=4096 C=768 H=12 DH=64 M=256, fp32 in/out, fp16 MFMA everywhere.
// Round 4: fix PKRTZ return-type mismatch (bit_cast __fp16x2 -> _Float16x2).
// MFMA-ized phi stages (kv_fused / attn_fused flash-style kernels):
//   GEMM1 -> exp2 -> P via LDS (C/D->A-operand transform) -> GEMM2,
//   with k_sum / normalizer folded in via fdot2 on the A-fragments.
// V stored transposed [bh][d][n] so GEMM2 B-frags are contiguous ds_read_b128.

#define LOG2E 1.44269504088896340736f

typedef _Float16 half8 __attribute__((ext_vector_type(8)));
typedef _Float16 half4_t __attribute__((ext_vector_type(4)));
typedef _Float16 half2_t __attribute__((ext_vector_type(2)));
typedef float f32x4 __attribute__((ext_vector_type(4)));

#if __has_builtin(__builtin_amdgcn_fdot2)
#define FDOT2(a, b, c) __builtin_amdgcn_fdot2((a), (b), (c), false)
#else
#define FDOT2(a, b, c) \
  ((float)(a)[0] * (float)(b)[0] + ((float)(a)[1] * (float)(b)[1] + (c)))
#endif

static __device__ __forceinline__ half2_t pk2(float a, float b) {
#if __has_builtin(__builtin_amdgcn_cvt_pkrtz)
  return __builtin_bit_cast(half2_t, __builtin_amdgcn_cvt_pkrtz(a, b));
#else
  half2_t r; r[0] = (_Float16)a; r[1] = (_Float16)b; return r;
#endif
}

// ---------------- casts ----------------

__global__ __launch_bounds__(256) void cast_f32_f16(const float* __restrict__ in,
                                                    _Float16* __restrict__ out, long n) {
  long i = ((long)blockIdx.x * 256 + threadIdx.x) * 4;
  if (i + 3 < n) {
    float4 v = *(const float4*)(in + i);
    half4_t h;
    h[0] = (_Float16)v.x; h[1] = (_Float16)v.y; h[2] = (_Float16)v.z; h[3] = (_Float16)v.w;
    *(half4_t*)(out + i) = h;
  } else {
    for (long j = i; j < n && j < i + 4; ++j) out[j] = (_Float16)in[j];
  }
}

// in [K, Nt] fp32 -> out [Nt, K] fp16
__global__ __launch_bounds__(256) void cast_transpose(const float* __restrict__ in,
                                                      _Float16* __restrict__ out,
                                                      int K, int Nt) {
  long i = (long)blockIdx.x * 256 + threadIdx.x;
  if (i >= (long)K * Nt) return;
  int n = (int)(i % Nt);
  int k = (int)(i / Nt);
  out[(long)n * K + k] = (_Float16)in[i];
}

// ---------------- MFMA GEMM (m97-style, 128x128x32, fp16 in) ----------------
// A [Mr,K] row-major fp16, BT [Ntot,K] row-major fp16. K % 32 == 0.
// EPI==1: Co = A@B + bias[col] + resid[row,col]  (fp32, proj+residual)
// EPI==2: scatter fp16 into qh/kh [bh][n][64] and vT [bh][d][n]  (qkv GEMM)

__device__ __forceinline__ void glds16(const _Float16* g, _Float16* s) {
  __builtin_amdgcn_global_load_lds(
      (const __attribute__((address_space(1))) void*)g,
      (__attribute__((address_space(3))) unsigned int*)s,
      16, 0, 0);
}

template <int EPI>
__global__ __launch_bounds__(256)
void gemm_f16(const _Float16* __restrict__ A, const _Float16* __restrict__ BT,
              float* __restrict__ Co, int Mr, int Ntot, int K,
              const float* __restrict__ bias, const float* __restrict__ resid,
              _Float16* __restrict__ qh, _Float16* __restrict__ kh,
              _Float16* __restrict__ vT) {
  __shared__ __align__(16) _Float16 As[128 * 32];
  __shared__ __align__(16) _Float16 Bs[128 * 32];
  const int tid = threadIdx.x;
  const int w = tid >> 6;
  const int l = tid & 63;
  const int lr = l & 15;
  const int kg = l >> 4;
  const int m0 = blockIdx.y * 128;
  const int n0 = blockIdx.x * 128;
  const int wm = (w >> 1) * 64;
  const int wn = (w & 1) * 64;

  const _Float16* gA = A + (long)(m0 + w * 32 + (l >> 2)) * K + (l & 3) * 8;
  const _Float16* gB = BT + (long)(n0 + w * 32 + (l >> 2)) * K + (l & 3) * 8;
  _Float16* sA = As + (w * 32) * 32;
  _Float16* sB = Bs + (w * 32) * 32;

  f32x4 acc[4][4];
#pragma unroll
  for (int t = 0; t < 4; ++t)
#pragma unroll
    for (int u = 0; u < 4; ++u) acc[t][u] = (f32x4){0.f, 0.f, 0.f, 0.f};

  const int nK = K >> 5;
  for (int kc = 0; kc < nK; ++kc) {
    __syncthreads();
    glds16(gA, sA);
    glds16(gA + 16 * K, sA + 16 * 32);
    glds16(gB, sB);
    glds16(gB + 16 * K, sB + 16 * 32);
    gA += 32; gB += 32;
    __syncthreads();

    half8 af[4], bf[4];
#pragma unroll
    for (int t = 0; t < 4; ++t)
      af[t] = *(const half8*)(As + (wm + t * 16 + lr) * 32 + kg * 8);
#pragma unroll
    for (int u = 0; u < 4; ++u)
      bf[u] = *(const half8*)(Bs + (wn + u * 16 + lr) * 32 + kg * 8);
#pragma unroll
    for (int t = 0; t < 4; ++t)
#pragma unroll
      for (int u = 0; u < 4; ++u)
        acc[t][u] = __builtin_amdgcn_mfma_f32_16x16x32_f16(af[t], bf[u], acc[t][u], 0, 0, 0);
  }

  // C/D layout: col = lane&15, row = (lane>>4)*4 + reg  [m89-verified]
#pragma unroll
  for (int t = 0; t < 4; ++t)
#pragma unroll
    for (int u = 0; u < 4; ++u) {
      const int row = m0 + wm + t * 16 + kg * 4;
      const int col = n0 + wn + u * 16 + lr;
      if (EPI == 1) {
#pragma unroll
        for (int r = 0; r < 4; ++r) {
          long idx = (long)(row + r) * Ntot + col;
          Co[idx] = acc[t][u][r] + bias[col] + resid[idx];
        }
      } else {
        const int which = (col >= 1536) ? 2 : ((col >= 768) ? 1 : 0);
        const int c2 = col - which * 768;
        const int h = c2 >> 6, d = c2 & 63;
        const int b_ = row >> 12, n_ = row & 4095;
        if (which == 2) {
          // vT [bh][d][n]: 4 consecutive n -> packed 8B store
          half4_t p4;
#pragma unroll
          for (int r = 0; r < 4; ++r) p4[r] = (_Float16)acc[t][u][r];
          *(half4_t*)(vT + ((long)(b_ * 12 + h) * 64 + d) * 4096 + n_) = p4;
        } else {
          _Float16* dst = (which == 0) ? qh : kh;
#pragma unroll
          for (int r = 0; r < 4; ++r)
            dst[((long)(b_ * 12 + h) * 4096 + n_ + r) * 64 + d] = (_Float16)acc[t][u][r];
        }
      }
    }
}

// ---------------- norm_sq with exp2-folded scale ----------------
// nsqL = 0.5*||.||^2 * LOG2E + 4  so  phi = exp2(p*LOG2E - nsqL)
// (the +4 folds the 1/sqrt(M)=1/16 = 2^-4 scale into the exponent)

__global__ __launch_bounds__(256)
void nsq_kernel(const _Float16* __restrict__ qh, const _Float16* __restrict__ kh,
                float* __restrict__ nsqLq, float* __restrict__ nsqLk) {
  long idx = (long)blockIdx.x * 256 + threadIdx.x;  // 96*4096
  const long base = idx * 64;
  float sq = 0.f, sk = 0.f;
#pragma unroll
  for (int d = 0; d < 64; d += 8) {
    half8 a = *(const half8*)(qh + base + d);
    half8 c = *(const half8*)(kh + base + d);
#pragma unroll
    for (int j = 0; j < 8; ++j) {
      float fa = (float)a[j], fc = (float)c[j];
      sq += fa * fa;
      sk += fc * fc;
    }
  }
  nsqLq[idx] = 0.5f * sq * LOG2E + 4.0f;
  nsqLk[idx] = 0.5f * sk * LOG2E + 4.0f;
}

// ---------------- fused phi_k -> kv stage ----------------
// grid (16 chunks, 96 bh), 256 thr. Per 64-token tile:
//  GEMM1: S[tok, m-slab] = K_tile @ RF^T  (A=K rows tok, B=RF from regs)
//  exp2 epilogue -> P_lds [m][tok] (packed b64: C/D reg-consecutive rows=tok)
//  GEMM2: kv[m-slab, d] += P @ V^T  (A=P_lds, B=VT_lds), ksum from A-frags.

__global__ __launch_bounds__(256)
void kv_fused(const _Float16* __restrict__ kh, const _Float16* __restrict__ vT,
              const _Float16* __restrict__ rfh, const float* __restrict__ nsqLk,
              _Float16* __restrict__ kvpart, float* __restrict__ kspart) {
  __shared__ __align__(16) _Float16 Ka[64 * 32], Kb[64 * 32];   // K tok d:0-32 / 32-64
  __shared__ __align__(16) _Float16 Va[64 * 32], Vb[64 * 32];   // VT d, tok 0-32 / 32-64
  __shared__ __align__(16) _Float16 P[256 * 72];                // [m][tok], pitch 72
  const int chunk = blockIdx.x, bh = blockIdx.y;
  const int tid = threadIdx.x, w = tid >> 6, l = tid & 63;
  const int lr = l & 15, kg = l >> 4;
  const long khbase = (long)bh * 4096 * 64;
  const long vtbase = (long)bh * 64 * 4096;
  const half2_t ONES = {(_Float16)1.f, (_Float16)1.f};

  // RF B-frags (GEMM1): B[k=d][col=m], m = w*64 + u*16 + lr
  half8 rf[4][2];
#pragma unroll
  for (int u = 0; u < 4; ++u)
#pragma unroll
    for (int ks = 0; ks < 2; ++ks)
      rf[u][ks] = *(const half8*)(rfh + (w * 64 + u * 16 + lr) * 64 + ks * 32 + kg * 8);

  f32x4 kvacc[4][4];
#pragma unroll
  for (int mt = 0; mt < 4; ++mt)
#pragma unroll
    for (int dt = 0; dt < 4; ++dt) kvacc[mt][dt] = (f32x4){0.f, 0.f, 0.f, 0.f};
  float ksacc[4] = {0.f, 0.f, 0.f, 0.f};

  for (int t8 = 0; t8 < 4; ++t8) {
    const int nt = chunk * 256 + t8 * 64;
    __syncthreads();
    if (w == 0) {
#pragma unroll
      for (int j = 0; j < 4; ++j)
        glds16(kh + khbase + (long)(nt + j * 16 + (l >> 2)) * 64 + (l & 3) * 8, Ka + j * 512);
    } else if (w == 1) {
#pragma unroll
      for (int j = 0; j < 4; ++j)
        glds16(kh + khbase + (long)(nt + j * 16 + (l >> 2)) * 64 + 32 + (l & 3) * 8, Kb + j * 512);
    } else if (w == 2) {
#pragma unroll
      for (int j = 0; j < 4; ++j)
        glds16(vT + vtbase + (long)(j * 16 + (l >> 2)) * 4096 + nt + (l & 3) * 8, Va + j * 512);
    } else {
#pragma unroll
      for (int j = 0; j < 4; ++j)
        glds16(vT + vtbase + (long)(j * 16 + (l >> 2)) * 4096 + nt + 32 + (l & 3) * 8, Vb + j * 512);
    }
    __syncthreads();

    // GEMM1
    half8 af[4][2];
#pragma unroll
    for (int tt = 0; tt < 4; ++tt) {
      af[tt][0] = *(const half8*)(Ka + (tt * 16 + lr) * 32 + kg * 8);
      af[tt][1] = *(const half8*)(Kb + (tt * 16 + lr) * 32 + kg * 8);
    }
    f32x4 sacc[4][4];
#pragma unroll
    for (int tt = 0; tt < 4; ++tt)
#pragma unroll
      for (int u = 0; u < 4; ++u) sacc[tt][u] = (f32x4){0.f, 0.f, 0.f, 0.f};
#pragma unroll
    for (int ks = 0; ks < 2; ++ks)
#pragma unroll
      for (int tt = 0; tt < 4; ++tt)
#pragma unroll
        for (int u = 0; u < 4; ++u)
          sacc[tt][u] = __builtin_amdgcn_mfma_f32_16x16x32_f16(af[tt][ks], rf[u][ks],
                                                               sacc[tt][u], 0, 0, 0);
    // exp2 + pack -> P[m][tok]
    float4 nsq4[4];
#pragma unroll
    for (int tt = 0; tt < 4; ++tt)
      nsq4[tt] = *(const float4*)(nsqLk + (long)bh * 4096 + nt + tt * 16 + kg * 4);
#pragma unroll
    for (int tt = 0; tt < 4; ++tt)
#pragma unroll
      for (int u = 0; u < 4; ++u) {
        float e0 = exp2f(sacc[tt][u][0] * LOG2E - nsq4[tt].x);
        float e1 = exp2f(sacc[tt][u][1] * LOG2E - nsq4[tt].y);
        float e2 = exp2f(sacc[tt][u][2] * LOG2E - nsq4[tt].z);
        float e3 = exp2f(sacc[tt][u][3] * LOG2E - nsq4[tt].w);
        half2_t h01 = pk2(e0, e1), h23 = pk2(e2, e3);
        half4_t p4; p4[0] = h01[0]; p4[1] = h01[1]; p4[2] = h23[0]; p4[3] = h23[1];
        *(half4_t*)(P + (w * 64 + u * 16 + lr) * 72 + tt * 16 + kg * 4) = p4;
      }
    // P region is wave-private (rows w*64..w*64+64): no barrier needed.

    // GEMM2 + ksum
#pragma unroll
    for (int ks = 0; ks < 2; ++ks) {
      half8 pa[4], bv[4];
#pragma unroll
      for (int mt = 0; mt < 4; ++mt)
        pa[mt] = *(const half8*)(P + (w * 64 + mt * 16 + lr) * 72 + ks * 32 + kg * 8);
#pragma unroll
      for (int dt = 0; dt < 4; ++dt)
        bv[dt] = *(const half8*)((ks == 0 ? Va : Vb) + (dt * 16 + lr) * 32 + kg * 8);
#pragma unroll
      for (int mt = 0; mt < 4; ++mt)
#pragma unroll
        for (int dt = 0; dt < 4; ++dt)
          kvacc[mt][dt] = __builtin_amdgcn_mfma_f32_16x16x32_f16(pa[mt], bv[dt],
                                                                 kvacc[mt][dt], 0, 0, 0);
#pragma unroll
      for (int mt = 0; mt < 4; ++mt) {
        const half2_t* pp = (const half2_t*)&pa[mt];
#pragma unroll
        for (int p = 0; p < 4; ++p) ksacc[mt] = FDOT2(pp[p], ONES, ksacc[mt]);
      }
    }
  }

  // ksum: reduce over kg quads, write from lanes 0..15
#pragma unroll
  for (int mt = 0; mt < 4; ++mt) {
    float v = ksacc[mt];
    v += __shfl_xor(v, 16);
    v += __shfl_xor(v, 32);
    if (l < 16) kspart[((bh * 16 + chunk) << 8) + w * 64 + mt * 16 + l] = v;
  }
  // kv partials fp16
#pragma unroll
  for (int mt = 0; mt < 4; ++mt)
#pragma unroll
    for (int dt = 0; dt < 4; ++dt)
#pragma unroll
      for (int r = 0; r < 4; ++r)
        kvpart[(((long)(bh * 16 + chunk) * 256) + w * 64 + mt * 16 + kg * 4 + r) * 64 +
               dt * 16 + lr] = (_Float16)kvacc[mt][dt][r];
}

__global__ __launch_bounds__(256)
void reduce_kv(const _Float16* __restrict__ part, _Float16* __restrict__ kvT) {
  long i = (long)blockIdx.x * 256 + threadIdx.x;  // 96*16384
  const int bh = (int)(i >> 14);
  const int rem = (int)(i & 16383);
  const int m = rem >> 6, d = rem & 63;  // d fastest -> coalesced reads
  float s = 0.f;
#pragma unroll
  for (int c = 0; c < 16; ++c)
    s += (float)part[(((long)bh * 16 + c) * 256 + m) * 64 + d];
  kvT[(long)bh * 16384 + d * 256 + m] = (_Float16)s;
}

__global__ __launch_bounds__(256)
void reduce_ks(const float* __restrict__ part, _Float16* __restrict__ ksumh) {
  int i = blockIdx.x * 256 + threadIdx.x;  // 96*256
  int bh = i >> 8, m = i & 255;
  float s = 0.f;
#pragma unroll
  for (int c = 0; c < 16; ++c) s += part[((bh * 16 + c) << 8) + m];
  ksumh[i] = (_Float16)s;
}

// ---------------- fused phi_q -> out stage ----------------
// grid (16, 96). Per 64-token tile:
//  GEMM1: S^T[m-slab, tok] = RF @ Q^T  (reg-consecutive rows = m)
//  exp2 -> P_lds [tok][m] (packed b64), barrier (P shared across waves)
//  GEMM2: out[tok-slab, d] = P @ kv  (B = kvT_lds), normalizer via fdot2(A, ksum).

__global__ __launch_bounds__(256)
void attn_fused(const _Float16* __restrict__ qh, const _Float16* __restrict__ rfh,
                const float* __restrict__ nsqLq, const _Float16* __restrict__ kvT,
                const _Float16* __restrict__ ksumh, _Float16* __restrict__ attn) {
  __shared__ __align__(16) _Float16 Qa[64 * 32], Qb[64 * 32];
  __shared__ __align__(16) _Float16 KV[64 * 264];  // [d][m], pitch 264
  __shared__ __align__(16) _Float16 KS[256];
  __shared__ __align__(16) _Float16 P[64 * 264];   // [tok][m], pitch 264
  __shared__ __align__(16) float NS[64];
  const int chunk = blockIdx.x, bh = blockIdx.y;
  const int b = bh / 12, h = bh % 12;
  const int tid = threadIdx.x, w = tid >> 6, l = tid & 63;
  const int lr = l & 15, kg = l >> 4;

  // stage kvT + ksum once
  {
    const int d = tid >> 2, mb = (tid & 3) * 64;
#pragma unroll
    for (int j = 0; j < 8; ++j)
      *(half8*)(KV + d * 264 + mb + j * 8) =
          *(const half8*)(kvT + (long)bh * 16384 + d * 256 + mb + j * 8);
    if (tid < 32) *(half8*)(KS + tid * 8) = *(const half8*)(ksumh + bh * 256 + tid * 8);
  }

  // RF A-frags (GEMM1): A[m=lane&15][k=d], m-slab = w*64
  half8 rf[4][2];
#pragma unroll
  for (int mt = 0; mt < 4; ++mt)
#pragma unroll
    for (int ks = 0; ks < 2; ++ks)
      rf[mt][ks] = *(const half8*)(rfh + (w * 64 + mt * 16 + lr) * 64 + ks * 32 + kg * 8);

  for (int t8 = 0; t8 < 4; ++t8) {
    const int nt = chunk * 256 + t8 * 64;
    __syncthreads();
    if (w == 0) {
#pragma unroll
      for (int j = 0; j < 4; ++j)
        glds16(qh + ((long)bh * 4096 + nt + j * 16 + (l >> 2)) * 64 + (l & 3) * 8, Qa + j * 512);
    } else if (w == 1) {
#pragma unroll
      for (int j = 0; j < 4; ++j)
        glds16(qh + ((long)bh * 4096 + nt + j * 16 + (l >> 2)) * 64 + 32 + (l & 3) * 8, Qb + j * 512);
    }
    __syncthreads();

    // GEMM1: rows = m (w*64 + mt*16 + kg*4 + r), cols = tok (tt*16 + lr)
    half8 bq[4][2];
#pragma unroll
    for (int tt = 0; tt < 4; ++tt) {
      bq[tt][0] = *(const half8*)(Qa + (tt * 16 + lr) * 32 + kg * 8);
      bq[tt][1] = *(const half8*)(Qb + (tt * 16 + lr) * 32 + kg * 8);
    }
    f32x4 sacc[4][4];
#pragma unroll
    for (int mt = 0; mt < 4; ++mt)
#pragma unroll
      for (int tt = 0; tt < 4; ++tt) sacc[mt][tt] = (f32x4){0.f, 0.f, 0.f, 0.f};
#pragma unroll
    for (int ks = 0; ks < 2; ++ks)
#pragma unroll
      for (int mt = 0; mt < 4; ++mt)
#pragma unroll
        for (int tt = 0; tt < 4; ++tt)
          sacc[mt][tt] = __builtin_amdgcn_mfma_f32_16x16x32_f16(rf[mt][ks], bq[tt][ks],
                                                                sacc[mt][tt], 0, 0, 0);
    float nsqv[4];
#pragma unroll
    for (int tt = 0; tt < 4; ++tt)
      nsqv[tt] = nsqLq[(long)bh * 4096 + nt + tt * 16 + lr];
#pragma unroll
    for (int mt = 0; mt < 4; ++mt)
#pragma unroll
      for (int tt = 0; tt < 4; ++tt) {
        float e0 = exp2f(sacc[mt][tt][0] * LOG2E - nsqv[tt]);
        float e1 = exp2f(sacc[mt][tt][1] * LOG2E - nsqv[tt]);
        float e2 = exp2f(sacc[mt][tt][2] * LOG2E - nsqv[tt]);
        float e3 = exp2f(sacc[mt][tt][3] * LOG2E - nsqv[tt]);
        half2_t h01 = pk2(e0, e1), h23 = pk2(e2, e3);
        half4_t p4; p4[0] = h01[0]; p4[1] = h01[1]; p4[2] = h23[0]; p4[3] = h23[1];
        *(half4_t*)(P + (tt * 16 + lr) * 264 + w * 64 + mt * 16 + kg * 4) = p4;
      }
    __syncthreads();  // P shared across waves

    // GEMM2: wave w -> tok-slab w*16; contraction m = 256 (8 k-steps)
    f32x4 oacc[4];
#pragma unroll
    for (int u = 0; u < 4; ++u) oacc[u] = (f32x4){0.f, 0.f, 0.f, 0.f};
    float nacc = 0.f;
#pragma unroll
    for (int ks = 0; ks < 8; ++ks) {
      half8 ap = *(const half8*)(P + (w * 16 + lr) * 264 + ks * 32 + kg * 8);
      half8 kv8 = *(const half8*)(KS + ks * 32 + kg * 8);
      const half2_t* a2 = (const half2_t*)&ap;
      const half2_t* k2 = (const half2_t*)&kv8;
#pragma unroll
      for (int p = 0; p < 4; ++p) nacc = FDOT2(a2[p], k2[p], nacc);
#pragma unroll
      for (int u = 0; u < 4; ++u) {
        half8 bkv = *(const half8*)(KV + (u * 16 + lr) * 264 + ks * 32 + kg * 8);
        oacc[u] = __builtin_amdgcn_mfma_f32_16x16x32_f16(ap, bkv, oacc[u], 0, 0, 0);
      }
    }
    nacc += __shfl_xor(nacc, 16);
    nacc += __shfl_xor(nacc, 32);
    if (l < 16) NS[w * 16 + l] = nacc;
    // same-wave LDS write->read; compiler inserts lgkmcnt wait
    f32x4 n4 = *(const f32x4*)(NS + w * 16 + kg * 4);
    float inv[4];
#pragma unroll
    for (int r = 0; r < 4; ++r) inv[r] = 1.f / (n4[r] + 1e-6f);
#pragma unroll
    for (int u = 0; u < 4; ++u)
#pragma unroll
      for (int r = 0; r < 4; ++r)
        attn[((long)b * 4096 + nt + w * 16 + kg * 4 + r) * 768 + h * 64 + u * 16 + lr] =
            (_Float16)(oacc[u][r] * inv[r]);
  }
}

// ---------------- LayerNorm: one wave per row of 768 (in-place safe) ----------------

__global__ __launch_bounds__(256)
void ln_kernel(const float* __restrict__ y, const float* __restrict__ gamma,
               const float* __restrict__ beta, float* __restrict__ outp) {
  const int wv = threadIdx.x >> 6, l = threadIdx.x & 63;
  const long row = (long)blockIdx.x * 4 + wv;
  const float* yr = y + row * 768;
  float v[12];
  float s = 0.f;
#pragma unroll
  for (int j = 0; j < 12; ++j) { v[j] = yr[l + j * 64]; s += v[j]; }
#pragma unroll
  for (int off = 32; off; off >>= 1) s += __shfl_xor(s, off);
  const float mu = s * (1.f / 768.f);
  float vs = 0.f;
#pragma unroll
  for (int j = 0; j < 12; ++j) { float d = v[j] - mu; vs += d * d; }
#pragma unroll
  for (int off = 32; off; off >>= 1) vs += __shfl_xor(vs, off);
  const float rstd = rsqrtf(vs * (1.f / 768.f) + 1e-5f);
  float* orp = outp + row * 768;
#pragma unroll
  for (int j = 0; j < 12; ++j)
    orp[l + j * 64] = (v[j] - mu) * rstd * gamma[l + j * 64] + beta[l + j * 64];
}

// ---------------- launch ----------------

extern "C" void kernel_launch(void* const* d_in, const int* in_sizes, int n_in,
                              void* d_out, int out_size, void* d_ws, size_t ws_size,
                              hipStream_t stream) {
  const float* x = (const float*)d_in[0];
  const float* Wqkv = (const float*)d_in[1];
  const float* Wproj = (const float*)d_in[2];
  const float* bproj = (const float*)d_in[3];
  const float* gamma = (const float*)d_in[4];
  const float* beta = (const float*)d_in[5];
  const float* rfm = (const float*)d_in[6];

  char* ws = (char*)d_ws;
  size_t off = 0;
  auto alloc = [&](size_t bytes) -> void* {
    void* p = ws + off;
    off += (bytes + 255) & ~(size_t)255;
    return p;
  };
  // region A (48MiB), time-shared: x_h [1..5] -> kvpart [7..8] -> attn [9..10]
  char* regionA = (char*)alloc(50331648ULL);
  _Float16* x_h = (_Float16*)regionA;
  _Float16* kvpart = (_Float16*)regionA;  // 96*16*256*64*2 = 50331648
  _Float16* attn = (_Float16*)regionA;    // 32768*768*2    = 50331648

  _Float16* wqkvT = (_Float16*)alloc(1769472ULL * 2);
  _Float16* wprojT = (_Float16*)alloc(589824ULL * 2);
  _Float16* rfh = (_Float16*)alloc(16384ULL * 2);
  _Float16* qh = (_Float16*)alloc(25165824ULL * 2);   // [bh][n][64]
  _Float16* kh = (_Float16*)alloc(25165824ULL * 2);   // [bh][n][64]
  _Float16* vT = (_Float16*)alloc(25165824ULL * 2);   // [bh][64][n]
  float* nsqLq = (float*)alloc(393216ULL * 4);
  float* nsqLk = (float*)alloc(393216ULL * 4);
  float* kspart = (float*)alloc(96ULL * 16 * 256 * 4);
  _Float16* kvT = (_Float16*)alloc(96ULL * 16384 * 2);  // [bh][d][m]
  _Float16* ksumh = (_Float16*)alloc(96ULL * 256 * 2);
  // total ~207 MB

  float* y = (float*)d_out;

  cast_f32_f16<<<24576, 256, 0, stream>>>(x, x_h, 25165824L);
  cast_transpose<<<6912, 256, 0, stream>>>(Wqkv, wqkvT, 768, 2304);
  cast_transpose<<<2304, 256, 0, stream>>>(Wproj, wprojT, 768, 768);
  cast_f32_f16<<<16, 256, 0, stream>>>(rfm, rfh, 16384L);
  gemm_f16<2><<<dim3(18, 256), 256, 0, stream>>>(x_h, wqkvT, nullptr, 32768, 2304, 768,
                                                 nullptr, nullptr, qh, kh, vT);
  nsq_kernel<<<1536, 256, 0, stream>>>(qh, kh, nsqLq, nsqLk);
  kv_fused<<<dim3(16, 96), 256, 0, stream>>>(kh, vT, rfh, nsqLk, kvpart, kspart);
  reduce_kv<<<6144, 256, 0, stream>>>(kvpart, kvT);
  reduce_ks<<<96, 256, 0, stream>>>(kspart, ksumh);
  attn_fused<<<dim3(16, 96), 256, 0, stream>>>(qh, rfh, nsqLq, kvT, ksumh, attn);
  gemm_f16<1><<<dim3(6, 256), 256, 0, stream>>>(attn, wprojT, y, 32768, 768, 768,
                                                bproj, x, nullptr, nullptr, nullptr);
  ln_kernel<<<8192, 256, 0, stream>>>(y, gamma, beta, y);
}

// Round 5
// 621.625 us; speedup vs baseline: 2.2818x; 1.0610x over previous
//
#include <hip/hip_runtime.h>
#include <hip/hip_fp16.h>

// PerformerAttention fused pipeline, MI355X (gfx950).
// B=8 N=4096 C=768 H=12 DH=64 M=256, fp32 in/out, fp16 MFMA everywhere.
// Round 5:
//  - qkv GEMM transposed (A=weights, B=tokens): C/D reg-consecutive dim = d
//    -> packed half4 stores for q/k, wave-uniform head, and norm_sq fused
//    into the epilogue (computed from rounded fp16 for MFMA consistency).
//  - launches 12 -> 7 (merged prep casts, merged reduces).
//  - kv partials halved (8 chunks).

#define LOG2E 1.44269504088896340736f

typedef _Float16 half8 __attribute__((ext_vector_type(8)));
typedef _Float16 half4_t __attribute__((ext_vector_type(4)));
typedef _Float16 half2_t __attribute__((ext_vector_type(2)));
typedef float f32x4 __attribute__((ext_vector_type(4)));

#if __has_builtin(__builtin_amdgcn_fdot2)
#define FDOT2(a, b, c) __builtin_amdgcn_fdot2((a), (b), (c), false)
#else
#define FDOT2(a, b, c) \
  ((float)(a)[0] * (float)(b)[0] + ((float)(a)[1] * (float)(b)[1] + (c)))
#endif

static __device__ __forceinline__ half2_t pk2(float a, float b) {
#if __has_builtin(__builtin_amdgcn_cvt_pkrtz)
  return __builtin_bit_cast(half2_t, __builtin_amdgcn_cvt_pkrtz(a, b));
#else
  half2_t r; r[0] = (_Float16)a; r[1] = (_Float16)b; return r;
#endif
}

__device__ __forceinline__ void glds16(const _Float16* g, _Float16* s) {
  __builtin_amdgcn_global_load_lds(
      (const __attribute__((address_space(1))) void*)g,
      (__attribute__((address_space(3))) unsigned int*)s,
      16, 0, 0);
}

// ---------------- merged prep: x cast (vec4) + weight transposes + rf cast ----------------

__global__ __launch_bounds__(256)
void prep(const float* __restrict__ x, const float* __restrict__ Wqkv,
          const float* __restrict__ Wproj, const float* __restrict__ rfm,
          _Float16* __restrict__ x_h, _Float16* __restrict__ wqkvT,
          _Float16* __restrict__ wprojT, _Float16* __restrict__ rfh) {
  const long bid = blockIdx.x;
  if (bid < 24576) {  // x: 25165824 = 24576*256*4 exactly
    long i = (bid * 256 + threadIdx.x) * 4;
    float4 v = *(const float4*)(x + i);
    half4_t h;
    h[0] = (_Float16)v.x; h[1] = (_Float16)v.y; h[2] = (_Float16)v.z; h[3] = (_Float16)v.w;
    *(half4_t*)(x_h + i) = h;
    return;
  }
  long idx = (bid - 24576) * 256 + threadIdx.x;  // 2375680 = 9280*256 exactly
  if (idx < 1769472) {          // W_qkv [768][2304] -> wqkvT [2304][768]
    int k = (int)(idx / 2304), n = (int)(idx % 2304);
    wqkvT[(long)n * 768 + k] = (_Float16)Wqkv[idx];
  } else if ((idx -= 1769472) < 589824) {  // W_proj [768][768] -> wprojT
    int k = (int)(idx / 768), n = (int)(idx % 768);
    wprojT[(long)n * 768 + k] = (_Float16)Wproj[idx];
  } else if ((idx -= 589824) < 16384) {
    rfh[idx] = (_Float16)rfm[idx];
  }
}

// ---------------- qkv GEMM, transposed (A=W rows 2304, B=x tokens) ----------------
// C^T: C/D row = weight-dim (which/head/d), col = token. Per wave the 64 rows
// cover exactly one head -> packed half4 q/k stores + fused norm_sq.
// grid (18 m-tiles = x-fastest, 256 token-tiles): W streams via L2, x read ~once.

__global__ __launch_bounds__(256)
void gemm_qkv(const _Float16* __restrict__ W, const _Float16* __restrict__ X,
              _Float16* __restrict__ qh, _Float16* __restrict__ kh,
              _Float16* __restrict__ vT,
              float* __restrict__ nsqLq, float* __restrict__ nsqLk) {
  __shared__ __align__(16) _Float16 As[128 * 32];
  __shared__ __align__(16) _Float16 Bs[128 * 32];
  const int tid = threadIdx.x;
  const int w = tid >> 6, l = tid & 63;
  const int lr = l & 15, kg = l >> 4;
  const int m0 = blockIdx.x * 128;   // weight-dim tile (0..2304)
  const int n0 = blockIdx.y * 128;   // token tile (0..32768)
  const int wm = (w >> 1) * 64, wn = (w & 1) * 64;

  const _Float16* gA = W + (long)(m0 + w * 32 + (l >> 2)) * 768 + (l & 3) * 8;
  const _Float16* gB = X + (long)(n0 + w * 32 + (l >> 2)) * 768 + (l & 3) * 8;
  _Float16* sA = As + (w * 32) * 32;
  _Float16* sB = Bs + (w * 32) * 32;

  f32x4 acc[4][4];
#pragma unroll
  for (int t = 0; t < 4; ++t)
#pragma unroll
    for (int u = 0; u < 4; ++u) acc[t][u] = (f32x4){0.f, 0.f, 0.f, 0.f};

  for (int kc = 0; kc < 24; ++kc) {
    __syncthreads();
    glds16(gA, sA);
    glds16(gA + 16 * 768, sA + 16 * 32);
    glds16(gB, sB);
    glds16(gB + 16 * 768, sB + 16 * 32);
    gA += 32; gB += 32;
    __syncthreads();

    half8 af[4], bf[4];
#pragma unroll
    for (int t = 0; t < 4; ++t)
      af[t] = *(const half8*)(As + (wm + t * 16 + lr) * 32 + kg * 8);
#pragma unroll
    for (int u = 0; u < 4; ++u)
      bf[u] = *(const half8*)(Bs + (wn + u * 16 + lr) * 32 + kg * 8);
#pragma unroll
    for (int t = 0; t < 4; ++t)
#pragma unroll
      for (int u = 0; u < 4; ++u)
        acc[t][u] = __builtin_amdgcn_mfma_f32_16x16x32_f16(af[t], bf[u], acc[t][u], 0, 0, 0);
  }

  // Region is block-uniform; head is wave-uniform.
  const int which = (m0 >= 1536) ? 2 : ((m0 >= 768) ? 1 : 0);
  const int base = (m0 - which * 768) + wm;  // multiple of 64
  const int h = base >> 6;

  if (which < 2) {
    _Float16* dst = (which == 0) ? qh : kh;
    float* nd = (which == 0) ? nsqLq : nsqLk;
    float ns[4] = {0.f, 0.f, 0.f, 0.f};
#pragma unroll
    for (int u = 0; u < 4; ++u) {
      const int tok = n0 + wn + u * 16 + lr;
      const int b_ = tok >> 12, n_ = tok & 4095;
      const long rowbase = ((long)(b_ * 12 + h) * 4096 + n_) * 64;
#pragma unroll
      for (int t = 0; t < 4; ++t) {
        half2_t h01 = pk2(acc[t][u][0], acc[t][u][1]);
        half2_t h23 = pk2(acc[t][u][2], acc[t][u][3]);
        half4_t p4; p4[0] = h01[0]; p4[1] = h01[1]; p4[2] = h23[0]; p4[3] = h23[1];
        *(half4_t*)(dst + rowbase + t * 16 + kg * 4) = p4;
        // nsq from ROUNDED values (consistent with MFMA consumers)
#pragma unroll
        for (int r = 0; r < 4; ++r) { float f = (float)p4[r]; ns[u] += f * f; }
      }
    }
    // sum over kg groups (same lr,u across the 4 quads)
#pragma unroll
    for (int u = 0; u < 4; ++u) {
      float s = ns[u];
      s += __shfl_xor(s, 16);
      s += __shfl_xor(s, 32);
      if (kg == 0) {
        const int tok = n0 + wn + u * 16 + lr;
        const int b_ = tok >> 12, n_ = tok & 4095;
        nd[(long)(b_ * 12 + h) * 4096 + n_] = 0.5f * s * LOG2E + 4.0f;
      }
    }
  } else {
    // vT [bh][d][n]: lanes lr -> consecutive tokens -> 2B x16 = 32B segments
#pragma unroll
    for (int u = 0; u < 4; ++u) {
      const int tok = n0 + wn + u * 16 + lr;
      const int b_ = tok >> 12, n_ = tok & 4095;
      const long hb = (long)(b_ * 12 + h) * 64;
#pragma unroll
      for (int t = 0; t < 4; ++t)
#pragma unroll
        for (int r = 0; r < 4; ++r)
          vT[(hb + t * 16 + kg * 4 + r) * 4096 + n_] = (_Float16)acc[t][u][r];
    }
  }
}

// ---------------- proj GEMM (m97-style): y = attn @ Wproj + bias + x ----------------

__global__ __launch_bounds__(256)
void gemm_proj(const _Float16* __restrict__ A, const _Float16* __restrict__ BT,
               float* __restrict__ Co, const float* __restrict__ bias,
               const float* __restrict__ resid) {
  __shared__ __align__(16) _Float16 As[128 * 32];
  __shared__ __align__(16) _Float16 Bs[128 * 32];
  const int tid = threadIdx.x;
  const int w = tid >> 6, l = tid & 63;
  const int lr = l & 15, kg = l >> 4;
  const int m0 = blockIdx.y * 128;
  const int n0 = blockIdx.x * 128;
  const int wm = (w >> 1) * 64, wn = (w & 1) * 64;

  const _Float16* gA = A + (long)(m0 + w * 32 + (l >> 2)) * 768 + (l & 3) * 8;
  const _Float16* gB = BT + (long)(n0 + w * 32 + (l >> 2)) * 768 + (l & 3) * 8;
  _Float16* sA = As + (w * 32) * 32;
  _Float16* sB = Bs + (w * 32) * 32;

  f32x4 acc[4][4];
#pragma unroll
  for (int t = 0; t < 4; ++t)
#pragma unroll
    for (int u = 0; u < 4; ++u) acc[t][u] = (f32x4){0.f, 0.f, 0.f, 0.f};

  for (int kc = 0; kc < 24; ++kc) {
    __syncthreads();
    glds16(gA, sA);
    glds16(gA + 16 * 768, sA + 16 * 32);
    glds16(gB, sB);
    glds16(gB + 16 * 768, sB + 16 * 32);
    gA += 32; gB += 32;
    __syncthreads();

    half8 af[4], bf[4];
#pragma unroll
    for (int t = 0; t < 4; ++t)
      af[t] = *(const half8*)(As + (wm + t * 16 + lr) * 32 + kg * 8);
#pragma unroll
    for (int u = 0; u < 4; ++u)
      bf[u] = *(const half8*)(Bs + (wn + u * 16 + lr) * 32 + kg * 8);
#pragma unroll
    for (int t = 0; t < 4; ++t)
#pragma unroll
      for (int u = 0; u < 4; ++u)
        acc[t][u] = __builtin_amdgcn_mfma_f32_16x16x32_f16(af[t], bf[u], acc[t][u], 0, 0, 0);
  }

#pragma unroll
  for (int u = 0; u < 4; ++u) {
    const int col = n0 + wn + u * 16 + lr;
    const float bv = bias[col];
#pragma unroll
    for (int t = 0; t < 4; ++t) {
      const int row = m0 + wm + t * 16 + kg * 4;
#pragma unroll
      for (int r = 0; r < 4; ++r) {
        long idx = (long)(row + r) * 768 + col;
        Co[idx] = acc[t][u][r] + bv + resid[idx];
      }
    }
  }
}

// ---------------- fused phi_k -> kv stage (8 chunks of 512 tokens) ----------------

__global__ __launch_bounds__(256)
void kv_fused(const _Float16* __restrict__ kh, const _Float16* __restrict__ vT,
              const _Float16* __restrict__ rfh, const float* __restrict__ nsqLk,
              _Float16* __restrict__ kvpart, float* __restrict__ kspart) {
  __shared__ __align__(16) _Float16 Ka[64 * 32], Kb[64 * 32];
  __shared__ __align__(16) _Float16 Va[64 * 32], Vb[64 * 32];
  __shared__ __align__(16) _Float16 P[256 * 72];
  const int chunk = blockIdx.x, bh = blockIdx.y;
  const int tid = threadIdx.x, w = tid >> 6, l = tid & 63;
  const int lr = l & 15, kg = l >> 4;
  const long khbase = (long)bh * 4096 * 64;
  const long vtbase = (long)bh * 64 * 4096;
  const half2_t ONES = {(_Float16)1.f, (_Float16)1.f};

  half8 rf[4][2];
#pragma unroll
  for (int u = 0; u < 4; ++u)
#pragma unroll
    for (int ks = 0; ks < 2; ++ks)
      rf[u][ks] = *(const half8*)(rfh + (w * 64 + u * 16 + lr) * 64 + ks * 32 + kg * 8);

  f32x4 kvacc[4][4];
#pragma unroll
  for (int mt = 0; mt < 4; ++mt)
#pragma unroll
    for (int dt = 0; dt < 4; ++dt) kvacc[mt][dt] = (f32x4){0.f, 0.f, 0.f, 0.f};
  float ksacc[4] = {0.f, 0.f, 0.f, 0.f};

  for (int t8 = 0; t8 < 8; ++t8) {
    const int nt = chunk * 512 + t8 * 64;
    __syncthreads();
    if (w == 0) {
#pragma unroll
      for (int j = 0; j < 4; ++j)
        glds16(kh + khbase + (long)(nt + j * 16 + (l >> 2)) * 64 + (l & 3) * 8, Ka + j * 512);
    } else if (w == 1) {
#pragma unroll
      for (int j = 0; j < 4; ++j)
        glds16(kh + khbase + (long)(nt + j * 16 + (l >> 2)) * 64 + 32 + (l & 3) * 8, Kb + j * 512);
    } else if (w == 2) {
#pragma unroll
      for (int j = 0; j < 4; ++j)
        glds16(vT + vtbase + (long)(j * 16 + (l >> 2)) * 4096 + nt + (l & 3) * 8, Va + j * 512);
    } else {
#pragma unroll
      for (int j = 0; j < 4; ++j)
        glds16(vT + vtbase + (long)(j * 16 + (l >> 2)) * 4096 + nt + 32 + (l & 3) * 8, Vb + j * 512);
    }
    __syncthreads();

    half8 af[4][2];
#pragma unroll
    for (int tt = 0; tt < 4; ++tt) {
      af[tt][0] = *(const half8*)(Ka + (tt * 16 + lr) * 32 + kg * 8);
      af[tt][1] = *(const half8*)(Kb + (tt * 16 + lr) * 32 + kg * 8);
    }
    f32x4 sacc[4][4];
#pragma unroll
    for (int tt = 0; tt < 4; ++tt)
#pragma unroll
      for (int u = 0; u < 4; ++u) sacc[tt][u] = (f32x4){0.f, 0.f, 0.f, 0.f};
#pragma unroll
    for (int ks = 0; ks < 2; ++ks)
#pragma unroll
      for (int tt = 0; tt < 4; ++tt)
#pragma unroll
        for (int u = 0; u < 4; ++u)
          sacc[tt][u] = __builtin_amdgcn_mfma_f32_16x16x32_f16(af[tt][ks], rf[u][ks],
                                                               sacc[tt][u], 0, 0, 0);
    float4 nsq4[4];
#pragma unroll
    for (int tt = 0; tt < 4; ++tt)
      nsq4[tt] = *(const float4*)(nsqLk + (long)bh * 4096 + nt + tt * 16 + kg * 4);
#pragma unroll
    for (int tt = 0; tt < 4; ++tt)
#pragma unroll
      for (int u = 0; u < 4; ++u) {
        float e0 = exp2f(sacc[tt][u][0] * LOG2E - nsq4[tt].x);
        float e1 = exp2f(sacc[tt][u][1] * LOG2E - nsq4[tt].y);
        float e2 = exp2f(sacc[tt][u][2] * LOG2E - nsq4[tt].z);
        float e3 = exp2f(sacc[tt][u][3] * LOG2E - nsq4[tt].w);
        half2_t h01 = pk2(e0, e1), h23 = pk2(e2, e3);
        half4_t p4; p4[0] = h01[0]; p4[1] = h01[1]; p4[2] = h23[0]; p4[3] = h23[1];
        *(half4_t*)(P + (w * 64 + u * 16 + lr) * 72 + tt * 16 + kg * 4) = p4;
      }
    // P rows w*64..+64 are wave-private: no barrier needed.
#pragma unroll
    for (int ks = 0; ks < 2; ++ks) {
      half8 pa[4], bv[4];
#pragma unroll
      for (int mt = 0; mt < 4; ++mt)
        pa[mt] = *(const half8*)(P + (w * 64 + mt * 16 + lr) * 72 + ks * 32 + kg * 8);
#pragma unroll
      for (int dt = 0; dt < 4; ++dt)
        bv[dt] = *(const half8*)((ks == 0 ? Va : Vb) + (dt * 16 + lr) * 32 + kg * 8);
#pragma unroll
      for (int mt = 0; mt < 4; ++mt)
#pragma unroll
        for (int dt = 0; dt < 4; ++dt)
          kvacc[mt][dt] = __builtin_amdgcn_mfma_f32_16x16x32_f16(pa[mt], bv[dt],
                                                                 kvacc[mt][dt], 0, 0, 0);
#pragma unroll
      for (int mt = 0; mt < 4; ++mt) {
        const half2_t* pp = (const half2_t*)&pa[mt];
#pragma unroll
        for (int p = 0; p < 4; ++p) ksacc[mt] = FDOT2(pp[p], ONES, ksacc[mt]);
      }
    }
  }

#pragma unroll
  for (int mt = 0; mt < 4; ++mt) {
    float v = ksacc[mt];
    v += __shfl_xor(v, 16);
    v += __shfl_xor(v, 32);
    if (l < 16) kspart[((bh * 8 + chunk) << 8) + w * 64 + mt * 16 + l] = v;
  }
#pragma unroll
  for (int mt = 0; mt < 4; ++mt)
#pragma unroll
    for (int dt = 0; dt < 4; ++dt)
#pragma unroll
      for (int r = 0; r < 4; ++r)
        kvpart[(((long)(bh * 8 + chunk) * 256) + w * 64 + mt * 16 + kg * 4 + r) * 64 +
               dt * 16 + lr] = (_Float16)kvacc[mt][dt][r];
}

// ---------------- merged reductions: kv partials + ksum partials ----------------

__global__ __launch_bounds__(256)
void reduce_all(const _Float16* __restrict__ kvpart, const float* __restrict__ kspart,
                _Float16* __restrict__ kvT, _Float16* __restrict__ ksumh) {
  if (blockIdx.x < 6144) {
    long i = (long)blockIdx.x * 256 + threadIdx.x;  // 96*16384
    const int bh = (int)(i >> 14);
    const int rem = (int)(i & 16383);
    const int m = rem >> 6, d = rem & 63;
    float s = 0.f;
#pragma unroll
    for (int c = 0; c < 8; ++c)
      s += (float)kvpart[(((long)bh * 8 + c) * 256 + m) * 64 + d];
    kvT[(long)bh * 16384 + d * 256 + m] = (_Float16)s;
  } else {
    int i = (blockIdx.x - 6144) * 256 + threadIdx.x;  // 96*256
    int bh = i >> 8, m = i & 255;
    float s = 0.f;
#pragma unroll
    for (int c = 0; c < 8; ++c) s += kspart[((bh * 8 + c) << 8) + m];
    ksumh[i] = (_Float16)s;
  }
}

// ---------------- fused phi_q -> out stage ----------------

__global__ __launch_bounds__(256)
void attn_fused(const _Float16* __restrict__ qh, const _Float16* __restrict__ rfh,
                const float* __restrict__ nsqLq, const _Float16* __restrict__ kvT,
                const _Float16* __restrict__ ksumh, _Float16* __restrict__ attn) {
  __shared__ __align__(16) _Float16 Qa[64 * 32], Qb[64 * 32];
  __shared__ __align__(16) _Float16 KV[64 * 264];
  __shared__ __align__(16) _Float16 KS[256];
  __shared__ __align__(16) _Float16 P[64 * 264];
  __shared__ __align__(16) float NS[64];
  const int chunk = blockIdx.x, bh = blockIdx.y;
  const int b = bh / 12, h = bh % 12;
  const int tid = threadIdx.x, w = tid >> 6, l = tid & 63;
  const int lr = l & 15, kg = l >> 4;

  {
    const int d = tid >> 2, mb = (tid & 3) * 64;
#pragma unroll
    for (int j = 0; j < 8; ++j)
      *(half8*)(KV + d * 264 + mb + j * 8) =
          *(const half8*)(kvT + (long)bh * 16384 + d * 256 + mb + j * 8);
    if (tid < 32) *(half8*)(KS + tid * 8) = *(const half8*)(ksumh + bh * 256 + tid * 8);
  }

  half8 rf[4][2];
#pragma unroll
  for (int mt = 0; mt < 4; ++mt)
#pragma unroll
    for (int ks = 0; ks < 2; ++ks)
      rf[mt][ks] = *(const half8*)(rfh + (w * 64 + mt * 16 + lr) * 64 + ks * 32 + kg * 8);

  for (int t8 = 0; t8 < 4; ++t8) {
    const int nt = chunk * 256 + t8 * 64;
    __syncthreads();
    if (w == 0) {
#pragma unroll
      for (int j = 0; j < 4; ++j)
        glds16(qh + ((long)bh * 4096 + nt + j * 16 + (l >> 2)) * 64 + (l & 3) * 8, Qa + j * 512);
    } else if (w == 1) {
#pragma unroll
      for (int j = 0; j < 4; ++j)
        glds16(qh + ((long)bh * 4096 + nt + j * 16 + (l >> 2)) * 64 + 32 + (l & 3) * 8, Qb + j * 512);
    }
    __syncthreads();

    half8 bq[4][2];
#pragma unroll
    for (int tt = 0; tt < 4; ++tt) {
      bq[tt][0] = *(const half8*)(Qa + (tt * 16 + lr) * 32 + kg * 8);
      bq[tt][1] = *(const half8*)(Qb + (tt * 16 + lr) * 32 + kg * 8);
    }
    f32x4 sacc[4][4];
#pragma unroll
    for (int mt = 0; mt < 4; ++mt)
#pragma unroll
      for (int tt = 0; tt < 4; ++tt) sacc[mt][tt] = (f32x4){0.f, 0.f, 0.f, 0.f};
#pragma unroll
    for (int ks = 0; ks < 2; ++ks)
#pragma unroll
      for (int mt = 0; mt < 4; ++mt)
#pragma unroll
        for (int tt = 0; tt < 4; ++tt)
          sacc[mt][tt] = __builtin_amdgcn_mfma_f32_16x16x32_f16(rf[mt][ks], bq[tt][ks],
                                                                sacc[mt][tt], 0, 0, 0);
    float nsqv[4];
#pragma unroll
    for (int tt = 0; tt < 4; ++tt)
      nsqv[tt] = nsqLq[(long)bh * 4096 + nt + tt * 16 + lr];
#pragma unroll
    for (int mt = 0; mt < 4; ++mt)
#pragma unroll
      for (int tt = 0; tt < 4; ++tt) {
        float e0 = exp2f(sacc[mt][tt][0] * LOG2E - nsqv[tt]);
        float e1 = exp2f(sacc[mt][tt][1] * LOG2E - nsqv[tt]);
        float e2 = exp2f(sacc[mt][tt][2] * LOG2E - nsqv[tt]);
        float e3 = exp2f(sacc[mt][tt][3] * LOG2E - nsqv[tt]);
        half2_t h01 = pk2(e0, e1), h23 = pk2(e2, e3);
        half4_t p4; p4[0] = h01[0]; p4[1] = h01[1]; p4[2] = h23[0]; p4[3] = h23[1];
        *(half4_t*)(P + (tt * 16 + lr) * 264 + w * 64 + mt * 16 + kg * 4) = p4;
      }
    __syncthreads();

    f32x4 oacc[4];
#pragma unroll
    for (int u = 0; u < 4; ++u) oacc[u] = (f32x4){0.f, 0.f, 0.f, 0.f};
    float nacc = 0.f;
#pragma unroll
    for (int ks = 0; ks < 8; ++ks) {
      half8 ap = *(const half8*)(P + (w * 16 + lr) * 264 + ks * 32 + kg * 8);
      half8 kv8 = *(const half8*)(KS + ks * 32 + kg * 8);
      const half2_t* a2 = (const half2_t*)&ap;
      const half2_t* k2 = (const half2_t*)&kv8;
#pragma unroll
      for (int p = 0; p < 4; ++p) nacc = FDOT2(a2[p], k2[p], nacc);
#pragma unroll
      for (int u = 0; u < 4; ++u) {
        half8 bkv = *(const half8*)(KV + (u * 16 + lr) * 264 + ks * 32 + kg * 8);
        oacc[u] = __builtin_amdgcn_mfma_f32_16x16x32_f16(ap, bkv, oacc[u], 0, 0, 0);
      }
    }
    nacc += __shfl_xor(nacc, 16);
    nacc += __shfl_xor(nacc, 32);
    if (l < 16) NS[w * 16 + l] = nacc;
    f32x4 n4 = *(const f32x4*)(NS + w * 16 + kg * 4);
    float inv[4];
#pragma unroll
    for (int r = 0; r < 4; ++r) inv[r] = 1.f / (n4[r] + 1e-6f);
#pragma unroll
    for (int u = 0; u < 4; ++u)
#pragma unroll
      for (int r = 0; r < 4; ++r)
        attn[((long)b * 4096 + nt + w * 16 + kg * 4 + r) * 768 + h * 64 + u * 16 + lr] =
            (_Float16)(oacc[u][r] * inv[r]);
  }
}

// ---------------- LayerNorm: one wave per row of 768 (in-place safe) ----------------

__global__ __launch_bounds__(256)
void ln_kernel(const float* __restrict__ y, const float* __restrict__ gamma,
               const float* __restrict__ beta, float* __restrict__ outp) {
  const int wv = threadIdx.x >> 6, l = threadIdx.x & 63;
  const long row = (long)blockIdx.x * 4 + wv;
  const float* yr = y + row * 768;
  float v[12];
  float s = 0.f;
#pragma unroll
  for (int j = 0; j < 12; ++j) { v[j] = yr[l + j * 64]; s += v[j]; }
#pragma unroll
  for (int off = 32; off; off >>= 1) s += __shfl_xor(s, off);
  const float mu = s * (1.f / 768.f);
  float vs = 0.f;
#pragma unroll
  for (int j = 0; j < 12; ++j) { float d = v[j] - mu; vs += d * d; }
#pragma unroll
  for (int off = 32; off; off >>= 1) vs += __shfl_xor(vs, off);
  const float rstd = rsqrtf(vs * (1.f / 768.f) + 1e-5f);
  float* orp = outp + row * 768;
#pragma unroll
  for (int j = 0; j < 12; ++j)
    orp[l + j * 64] = (v[j] - mu) * rstd * gamma[l + j * 64] + beta[l + j * 64];
}

// ---------------- launch ----------------

extern "C" void kernel_launch(void* const* d_in, const int* in_sizes, int n_in,
                              void* d_out, int out_size, void* d_ws, size_t ws_size,
                              hipStream_t stream) {
  const float* x = (const float*)d_in[0];
  const float* Wqkv = (const float*)d_in[1];
  const float* Wproj = (const float*)d_in[2];
  const float* bproj = (const float*)d_in[3];
  const float* gamma = (const float*)d_in[4];
  const float* beta = (const float*)d_in[5];
  const float* rfm = (const float*)d_in[6];

  char* ws = (char*)d_ws;
  size_t off = 0;
  auto alloc = [&](size_t bytes) -> void* {
    void* p = ws + off;
    off += (bytes + 255) & ~(size_t)255;
    return p;
  };
  // region A (48MiB), time-shared: x_h -> kvpart -> attn
  char* regionA = (char*)alloc(50331648ULL);
  _Float16* x_h = (_Float16*)regionA;
  _Float16* kvpart = (_Float16*)regionA;  // 96*8*256*64*2 = 25165824 B
  _Float16* attn = (_Float16*)regionA;    // 32768*768*2   = 50331648 B

  _Float16* wqkvT = (_Float16*)alloc(1769472ULL * 2);
  _Float16* wprojT = (_Float16*)alloc(589824ULL * 2);
  _Float16* rfh = (_Float16*)alloc(16384ULL * 2);
  _Float16* qh = (_Float16*)alloc(25165824ULL * 2);   // [bh][n][64]
  _Float16* kh = (_Float16*)alloc(25165824ULL * 2);   // [bh][n][64]
  _Float16* vT = (_Float16*)alloc(25165824ULL * 2);   // [bh][64][n]
  float* nsqLq = (float*)alloc(393216ULL * 4);
  float* nsqLk = (float*)alloc(393216ULL * 4);
  float* kspart = (float*)alloc(96ULL * 8 * 256 * 4);
  _Float16* kvT = (_Float16*)alloc(96ULL * 16384 * 2);  // [bh][d][m]
  _Float16* ksumh = (_Float16*)alloc(96ULL * 256 * 2);
  // total ~207 MB

  float* y = (float*)d_out;

  prep<<<33856, 256, 0, stream>>>(x, Wqkv, Wproj, rfm, x_h, wqkvT, wprojT, rfh);
  gemm_qkv<<<dim3(18, 256), 256, 0, stream>>>(wqkvT, x_h, qh, kh, vT, nsqLq, nsqLk);
  kv_fused<<<dim3(8, 96), 256, 0, stream>>>(kh, vT, rfh, nsqLk, kvpart, kspart);
  reduce_all<<<6240, 256, 0, stream>>>(kvpart, kspart, kvT, ksumh);
  attn_fused<<<dim3(16, 96), 256, 0, stream>>>(qh, rfh, nsqLq, kvT, ksumh, attn);
  gemm_proj<<<dim3(6, 256), 256, 0, stream>>>(attn, wprojT, y, bproj, x);
  ln_kernel<<<8192, 256, 0, stream>>>(y, gamma, beta, y);
}